// Round 2
// baseline (7273.109 us; speedup 1.0000x reference)
//
#include <hip/hip_runtime.h>
#include <math.h>

// KERNEL_WIDTH = sqrt(9/pi)
#define KW_INV 0.5908179502964271f   // 1/sqrt(9/pi)

// Tube-of-response accumulation for one LOR.
// N* > 0 => compile-time dims (G=128 specialization); strides passed by the
// call site fold to constants when literal.
// Corner taps (|o0|==2 && |o1|==2) have min dist^2 = 4.5 > 9/pi, so w==0
// always -> skipped at compile time (21 of 25 taps survive).
template<int N0, int N1, int N2>
__device__ __forceinline__
float tor_lor(const float* __restrict__ img,
              const float* __restrict__ L,
              float lo0, float lo1, float lo2,
              float vs0, float vs1, float vs2,
              int n0_, int n1_, int n2_,
              int s0, int s1, int s2)
{
    const int n0 = N0 ? N0 : n0_;
    const int n1 = N1 ? N1 : n1_;
    const int n2 = N2 ? N2 : n2_;

    const float inv_vs0 = 1.0f / vs0;
    const float inv_vs1 = 1.0f / vs1;

    const float p1x = L[0], p1y = L[1], p1z = L[2];
    const float p2x = L[3], p2y = L[4], p2z = L[5];
    const float dx = p2x - p1x, dy = p2y - p1y, dz = p2z - p1z;
    const float len = sqrtf(dx * dx + dy * dy + dz * dz);
    const float inv_dz = 1.0f / dz;
    const float step = vs2 * len * fabsf(inv_dz);

    float acc_total = 0.0f;

    for (int k = 0; k < n2; ++k) {
        const float zc = lo2 + ((float)k + 0.5f) * vs2;
        const float t  = (zc - p1z) * inv_dz;
        const float cx = fmaf(t, dx, p1x);
        const float cy = fmaf(t, dy, p1y);
        const float fx = (cx - lo0) * inv_vs0 - 0.5f;
        const float fy = (cy - lo1) * inv_vs1 - 0.5f;
        const int ix = (int)rintf(fx);   // half-to-even == jnp.round
        const int iy = (int)rintf(fy);

        int   offx[5], offy[5];
        float ddx2[5], ddy2[5], mx[5], my[5];
#pragma unroll
        for (int u = 0; u < 5; ++u) {
            const int jx  = ix - 2 + u;
            const int jxc = min(max(jx, 0), n0 - 1);
            offx[u] = jxc * s0;
            const float dxx = (float)jx - fx;
            ddx2[u] = dxx * dxx;
            mx[u]   = ((unsigned)jx < (unsigned)n0) ? 1.0f : 0.0f;

            const int jy  = iy - 2 + u;
            const int jyc = min(max(jy, 0), n1 - 1);
            offy[u] = jyc * s1;
            const float dyy = (float)jy - fy;
            ddy2[u] = dyy * dyy;
            my[u]   = ((unsigned)jy < (unsigned)n1) ? 1.0f : 0.0f;
        }

        const int kb = k * s2;

        // Batch all (non-corner) tap loads: independent -> one waitcnt.
        float v[25];
#pragma unroll
        for (int u = 0; u < 5; ++u) {
#pragma unroll
            for (int w = 0; w < 5; ++w) {
                if ((u == 0 || u == 4) && (w == 0 || w == 4)) continue;
                v[u * 5 + w] = img[offx[u] + offy[w] + kb];
            }
        }

        float acc = 0.0f;
#pragma unroll
        for (int u = 0; u < 5; ++u) {
#pragma unroll
            for (int w = 0; w < 5; ++w) {
                if ((u == 0 || u == 4) && (w == 0 || w == 4)) continue;
                const float d2  = ddx2[u] + ddy2[w];
                float wgt = fmaxf(0.0f, fmaf(-sqrtf(d2), KW_INV, 1.0f));
                wgt *= mx[u] * my[w];
                acc = fmaf(wgt, v[u * 5 + w], acc);
            }
        }
        acc_total += acc;
    }

    return acc_total * step;
}

// Fused projection: one launch covers all 3 LOR sets (block ranges pick set).
// imgZ: original [G,G,G]; imgX: x-permuted copy (or original for dynamic path).
template<int GG>
__global__ __launch_bounds__(256)
void proj_fused(const float* __restrict__ imgZ,
                const float* __restrict__ imgX,
                const float* __restrict__ xlors,
                const float* __restrict__ ylors,
                const float* __restrict__ zlors,
                const float* __restrict__ center,
                const float* __restrict__ size_,
                float* __restrict__ out,
                int nx, int ny, int nz,
                int nbx, int nby,
                int G_,
                int sx0, int sx1, int sx2,
                int sy0, int sy1, int sy2,
                int sz0, int sz1, int sz2)
{
    const int b = blockIdx.x;
    const int G = GG ? GG : G_;

    if (b < nbx) {
        // px: perm (2,0,1)
        const int i = b * 256 + threadIdx.x;
        if (i >= nx) return;
        const float c0 = center[2], c1 = center[0], c2 = center[1];
        const float S0 = size_[2], S1 = size_[0], S2 = size_[1];
        const float vs0 = S0 / (float)G, vs1 = S1 / (float)G, vs2 = S2 / (float)G;
        const float* L = xlors + 6 * (size_t)i;
        float r;
        if (GG)
            r = tor_lor<GG, GG, GG>(imgX, L,
                    c0 - 0.5f * S0, c1 - 0.5f * S1, c2 - 0.5f * S2,
                    vs0, vs1, vs2, GG, GG, GG, GG * GG, GG, 1);
        else
            r = tor_lor<0, 0, 0>(imgX, L,
                    c0 - 0.5f * S0, c1 - 0.5f * S1, c2 - 0.5f * S2,
                    vs0, vs1, vs2, G, G, G, sx0, sx1, sx2);
        out[i] = r;
    } else if (b < nbx + nby) {
        // py: perm (1,0,2)
        const int i = (b - nbx) * 256 + threadIdx.x;
        if (i >= ny) return;
        const float c0 = center[1], c1 = center[0], c2 = center[2];
        const float S0 = size_[1], S1 = size_[0], S2 = size_[2];
        const float vs0 = S0 / (float)G, vs1 = S1 / (float)G, vs2 = S2 / (float)G;
        const float* L = ylors + 6 * (size_t)i;
        float r;
        if (GG)
            r = tor_lor<GG, GG, GG>(imgZ, L,
                    c0 - 0.5f * S0, c1 - 0.5f * S1, c2 - 0.5f * S2,
                    vs0, vs1, vs2, GG, GG, GG, GG, GG * GG, 1);
        else
            r = tor_lor<0, 0, 0>(imgZ, L,
                    c0 - 0.5f * S0, c1 - 0.5f * S1, c2 - 0.5f * S2,
                    vs0, vs1, vs2, G, G, G, sy0, sy1, sy2);
        out[nx + i] = r;
    } else {
        // pz: identity
        const int i = (b - nbx - nby) * 256 + threadIdx.x;
        if (i >= nz) return;
        const float c0 = center[0], c1 = center[1], c2 = center[2];
        const float S0 = size_[0], S1 = size_[1], S2 = size_[2];
        const float vs0 = S0 / (float)G, vs1 = S1 / (float)G, vs2 = S2 / (float)G;
        const float* L = zlors + 6 * (size_t)i;
        float r;
        if (GG)
            r = tor_lor<GG, GG, GG>(imgZ, L,
                    c0 - 0.5f * S0, c1 - 0.5f * S1, c2 - 0.5f * S2,
                    vs0, vs1, vs2, GG, GG, GG, GG * GG, GG, 1);
        else
            r = tor_lor<0, 0, 0>(imgZ, L,
                    c0 - 0.5f * S0, c1 - 0.5f * S1, c2 - 0.5f * S2,
                    vs0, vs1, vs2, G, G, G, sz0, sz1, sz2);
        out[nx + ny + i] = r;
    }
}

// 2D transpose: in[R][C] -> out[C][R].  (x-perm copy: image viewed as
// [R=G*G, C=G] transposed gives P_x[i0][i1][i2] = image[i1,i2,i0] with
// strides (G*G, G, 1).)  R, C divisible by 32.
__global__ __launch_bounds__(256)
void transpose_RC(const float* __restrict__ in, float* __restrict__ outp,
                  int R, int C)
{
    __shared__ float tile[32][33];
    const int rt = blockIdx.x * 32;
    const int ct = blockIdx.y * 32;
    const int tx = threadIdx.x;
    const int ty = threadIdx.y;   // block (32,8)
#pragma unroll
    for (int j = 0; j < 32; j += 8)
        tile[ty + j][tx] = in[(size_t)(rt + ty + j) * C + (ct + tx)];
    __syncthreads();
#pragma unroll
    for (int j = 0; j < 32; j += 8)
        outp[(size_t)(ct + ty + j) * R + (rt + tx)] = tile[tx][ty + j];
}

extern "C" void kernel_launch(void* const* d_in, const int* in_sizes, int n_in,
                              void* d_out, int out_size, void* d_ws, size_t ws_size,
                              hipStream_t stream)
{
    const float* img    = (const float*)d_in[0];
    const float* center = (const float*)d_in[2];
    const float* size_  = (const float*)d_in[3];
    const float* xlors  = (const float*)d_in[4];
    const float* ylors  = (const float*)d_in[5];
    const float* zlors  = (const float*)d_in[6];
    float* out = (float*)d_out;

    const int nx = in_sizes[4] / 6;
    const int ny = in_sizes[5] / 6;
    const int nz = in_sizes[6] / 6;

    // Derive G from image element count (grid values == image dims per setup).
    int G = (int)lround(cbrt((double)in_sizes[0]));

    const int B = 256;
    const int nbx = (nx + B - 1) / B;
    const int nby = (ny + B - 1) / B;
    const int nbz = (nz + B - 1) / B;
    const int nb  = nbx + nby + nbz;

    const bool fast = (G == 128) && (ws_size >= (size_t)G * G * G * sizeof(float));

    if (fast) {
        float* Px = (float*)d_ws;
        transpose_RC<<<dim3((G * G) / 32, G / 32), dim3(32, 8), 0, stream>>>(
            img, Px, G * G, G);
        proj_fused<128><<<nb, B, 0, stream>>>(
            img, Px, xlors, ylors, zlors, center, size_, out,
            nx, ny, nz, nbx, nby, G,
            0, 0, 0, 0, 0, 0, 0, 0, 0);
    } else {
        const int G2 = G * G;
        proj_fused<0><<<nb, B, 0, stream>>>(
            img, img, xlors, ylors, zlors, center, size_, out,
            nx, ny, nz, nbx, nby, G,
            /* x: perm (2,0,1) on original */ 1, G2, G,
            /* y: perm (1,0,2) on original */ G, G2, 1,
            /* z: identity                 */ G2, G, 1);
    }
}

// Round 3
// 1797.783 us; speedup vs baseline: 4.0456x; 4.0456x over previous
//
#include <hip/hip_runtime.h>
#include <math.h>

// KERNEL_WIDTH = sqrt(9/pi)
#define KW2_F  2.8647889756541161f   // (9/pi)
#define KW_INV 0.5908179502964271f   // 1/sqrt(9/pi)
#define BIGD2  1e30f

// ---------------------------------------------------------------------------
// k-chunked (x4, float4) tube-of-response for one LOR. Requires s2 == 1 and
// n2 % 4 == 0. img indexed as jx*s0 + jy*s1 + k.
// Reference semantics preserved exactly: a tap (jx,jy) contributes at slice k
// only if |jx-ix_k|<=2 && |jy-iy_k|<=2 (the 5x5 window) and is in-bounds;
// weight = max(0, 1 - dist/KW). Out-of-window/OOB taps get d2=BIGD2 -> w=0.
// ---------------------------------------------------------------------------
__device__ __forceinline__
float tor_lor4(const float* __restrict__ img,
               const float* __restrict__ L,
               float lo0, float lo1, float lo2,
               float vs0, float vs1, float vs2,
               int n0, int n1, int n2, int s0, int s1)
{
    const float inv_vs0 = 1.0f / vs0;
    const float inv_vs1 = 1.0f / vs1;

    const float p1x = L[0], p1y = L[1], p1z = L[2];
    const float p2x = L[3], p2y = L[4], p2z = L[5];
    const float dx = p2x - p1x, dy = p2y - p1y, dz = p2z - p1z;
    const float len = sqrtf(dx * dx + dy * dy + dz * dz);
    const float inv_dz = 1.0f / dz;
    const float step = vs2 * len * fabsf(inv_dz);

    float acc0 = 0.0f, acc1 = 0.0f, acc2 = 0.0f, acc3 = 0.0f;

    for (int k0 = 0; k0 < n2; k0 += 4) {
        float fx[4], fy[4];
        int ix[4], iy[4];
#pragma unroll
        for (int j = 0; j < 4; ++j) {
            const float zc = lo2 + ((float)(k0 + j) + 0.5f) * vs2;
            const float t  = (zc - p1z) * inv_dz;
            fx[j] = (fmaf(t, dx, p1x) - lo0) * inv_vs0 - 0.5f;
            fy[j] = (fmaf(t, dy, p1y) - lo1) * inv_vs1 - 0.5f;
            ix[j] = (int)rintf(fx[j]);   // half-to-even == jnp.round
            iy[j] = (int)rintf(fy[j]);
        }
        // fx,fy are affine (monotone) in k -> window bounds from endpoints.
        const int xlo = min(ix[0], ix[3]) - 2, xhi = max(ix[0], ix[3]) + 2;
        const int ylo = min(iy[0], iy[3]) - 2, yhi = max(iy[0], iy[3]) + 2;

        for (int jx = xlo; jx <= xhi; ++jx) {
            float ddx2[4];
            bool  xm[4];
            float rowmin = BIGD2;
#pragma unroll
            for (int j = 0; j < 4; ++j) {
                const float dxx = (float)jx - fx[j];
                ddx2[j] = dxx * dxx;
                xm[j] = ((unsigned)(jx - ix[j] + 2) <= 4u) &&
                        ((unsigned)jx < (unsigned)n0);
                rowmin = fminf(rowmin, xm[j] ? ddx2[j] : BIGD2);
            }
            if (rowmin >= KW2_F) continue;   // entire row weightless

            const int jxc  = min(max(jx, 0), n0 - 1);
            const int xoff = jxc * s0 + k0;

            for (int jy = ylo; jy <= yhi; ++jy) {
                float d2m[4];
                float dmin = BIGD2;
#pragma unroll
                for (int j = 0; j < 4; ++j) {
                    const float dyy = (float)jy - fy[j];
                    const float d2  = fmaf(dyy, dyy, ddx2[j]);
                    const bool m = xm[j] &&
                                   ((unsigned)(jy - iy[j] + 2) <= 4u) &&
                                   ((unsigned)jy < (unsigned)n1);
                    d2m[j] = m ? d2 : BIGD2;
                    dmin = fminf(dmin, d2m[j]);
                }
                if (dmin < KW2_F) {
                    const int jyc = min(max(jy, 0), n1 - 1);
                    const float4 v =
                        *reinterpret_cast<const float4*>(img + xoff + jyc * s1);
                    float wg[4];
#pragma unroll
                    for (int j = 0; j < 4; ++j)
                        wg[j] = fmaxf(0.0f, fmaf(-sqrtf(d2m[j]), KW_INV, 1.0f));
                    acc0 = fmaf(wg[0], v.x, acc0);
                    acc1 = fmaf(wg[1], v.y, acc1);
                    acc2 = fmaf(wg[2], v.z, acc2);
                    acc3 = fmaf(wg[3], v.w, acc3);
                }
            }
        }
    }
    return (acc0 + acc1 + acc2 + acc3) * step;
}

// Scalar guarded fallback (any strides / any n2).
__device__ __forceinline__
float tor_lor_s(const float* __restrict__ img,
                const float* __restrict__ L,
                float lo0, float lo1, float lo2,
                float vs0, float vs1, float vs2,
                int n0, int n1, int n2, int s0, int s1, int s2)
{
    const float inv_vs0 = 1.0f / vs0;
    const float inv_vs1 = 1.0f / vs1;
    const float p1x = L[0], p1y = L[1], p1z = L[2];
    const float p2x = L[3], p2y = L[4], p2z = L[5];
    const float dx = p2x - p1x, dy = p2y - p1y, dz = p2z - p1z;
    const float len = sqrtf(dx * dx + dy * dy + dz * dz);
    const float inv_dz = 1.0f / dz;
    const float step = vs2 * len * fabsf(inv_dz);

    float acc_total = 0.0f;
    for (int k = 0; k < n2; ++k) {
        const float zc = lo2 + ((float)k + 0.5f) * vs2;
        const float t  = (zc - p1z) * inv_dz;
        const float fx = (fmaf(t, dx, p1x) - lo0) * inv_vs0 - 0.5f;
        const float fy = (fmaf(t, dy, p1y) - lo1) * inv_vs1 - 0.5f;
        const int ix = (int)rintf(fx);
        const int iy = (int)rintf(fy);
        const int kb = k * s2;
        float acc = 0.0f;
#pragma unroll
        for (int o0 = -2; o0 <= 2; ++o0) {
            const int jx = ix + o0;
            if ((unsigned)jx >= (unsigned)n0) continue;
            const float dxx  = (float)jx - fx;
            const float ddx2 = dxx * dxx;
            if (ddx2 >= KW2_F) continue;
            const int xb = jx * s0 + kb;
#pragma unroll
            for (int o1 = -2; o1 <= 2; ++o1) {
                const int jy = iy + o1;
                if ((unsigned)jy >= (unsigned)n1) continue;
                const float dyy = (float)jy - fy;
                const float d2  = fmaf(dyy, dyy, ddx2);
                if (d2 < KW2_F) {
                    const float w = fmaf(-sqrtf(d2), KW_INV, 1.0f);
                    acc = fmaf(w, img[xb + jy * s1], acc);
                }
            }
        }
        acc_total += acc;
    }
    return acc_total * step;
}

// ---------------------------------------------------------------------------
// Fused launch: block ranges pick the LOR set. FOUR==1 -> float4 path
// (s2==1 for all sets; x uses the transposed copy imgX).
// ---------------------------------------------------------------------------
template<int FOUR>
__global__ __launch_bounds__(256)
void proj_fused(const float* __restrict__ imgZ,
                const float* __restrict__ imgX,
                const float* __restrict__ xlors,
                const float* __restrict__ ylors,
                const float* __restrict__ zlors,
                const float* __restrict__ center,
                const float* __restrict__ size_,
                float* __restrict__ out,
                int nx, int ny, int nz,
                int nbx, int nby, int G,
                int xs0, int xs1, int xs2)  // x-set strides (scalar path)
{
    const int b = blockIdx.x;
    const int G2 = G * G;

    const float* img;
    const float* lors;
    float* op;
    int n, a0, a1, a2, s0, s1, s2;

    if (b < nbx) {            // px: perm (2,0,1)
        const int i = b * 256 + threadIdx.x;
        if (i >= nx) return;
        img = FOUR ? imgX : imgZ;
        lors = xlors + 6 * (size_t)i;  op = out + i;  n = nx;
        a0 = 2; a1 = 0; a2 = 1;
        if (FOUR) { s0 = G2; s1 = G; s2 = 1; }
        else      { s0 = xs0; s1 = xs1; s2 = xs2; }
    } else if (b < nbx + nby) {  // py: perm (1,0,2)
        const int i = (b - nbx) * 256 + threadIdx.x;
        if (i >= ny) return;
        img = imgZ; lors = ylors + 6 * (size_t)i;  op = out + nx + i;  n = ny;
        a0 = 1; a1 = 0; a2 = 2;  s0 = G; s1 = G2; s2 = 1;
    } else {                     // pz: identity
        const int i = (b - nbx - nby) * 256 + threadIdx.x;
        if (i >= nz) return;
        img = imgZ; lors = zlors + 6 * (size_t)i;  op = out + nx + ny + i; n = nz;
        a0 = 0; a1 = 1; a2 = 2;  s0 = G2; s1 = G; s2 = 1;
    }
    (void)n;

    const float S0 = size_[a0], S1 = size_[a1], S2 = size_[a2];
    const float vs0 = S0 / (float)G, vs1 = S1 / (float)G, vs2 = S2 / (float)G;
    const float lo0 = center[a0] - 0.5f * S0;
    const float lo1 = center[a1] - 0.5f * S1;
    const float lo2 = center[a2] - 0.5f * S2;

    float r;
    if (FOUR)
        r = tor_lor4(img, lors, lo0, lo1, lo2, vs0, vs1, vs2,
                     G, G, G, s0, s1);
    else
        r = tor_lor_s(img, lors, lo0, lo1, lo2, vs0, vs1, vs2,
                      G, G, G, s0, s1, s2);
    *op = r;
}

// 2D transpose in[R][C] -> out[C][R]; Px[c,i0,i1] = image[i0,i1,c]
// giving the x-perm with strides (G^2, G, 1). R, C divisible by 32.
__global__ __launch_bounds__(256)
void transpose_RC(const float* __restrict__ in, float* __restrict__ outp,
                  int R, int C)
{
    __shared__ float tile[32][33];
    const int rt = blockIdx.x * 32;
    const int ct = blockIdx.y * 32;
    const int tx = threadIdx.x;
    const int ty = threadIdx.y;   // block (32,8)
#pragma unroll
    for (int j = 0; j < 32; j += 8)
        tile[ty + j][tx] = in[(size_t)(rt + ty + j) * C + (ct + tx)];
    __syncthreads();
#pragma unroll
    for (int j = 0; j < 32; j += 8)
        outp[(size_t)(ct + ty + j) * R + (rt + tx)] = tile[tx][ty + j];
}

extern "C" void kernel_launch(void* const* d_in, const int* in_sizes, int n_in,
                              void* d_out, int out_size, void* d_ws, size_t ws_size,
                              hipStream_t stream)
{
    const float* img    = (const float*)d_in[0];
    const float* center = (const float*)d_in[2];
    const float* size_  = (const float*)d_in[3];
    const float* xlors  = (const float*)d_in[4];
    const float* ylors  = (const float*)d_in[5];
    const float* zlors  = (const float*)d_in[6];
    float* out = (float*)d_out;

    const int nx = in_sizes[4] / 6;
    const int ny = in_sizes[5] / 6;
    const int nz = in_sizes[6] / 6;

    int G = (int)lround(cbrt((double)in_sizes[0]));
    const int G2 = G * G;

    const int B = 256;
    const int nbx = (nx + B - 1) / B;
    const int nby = (ny + B - 1) / B;
    const int nbz = (nz + B - 1) / B;
    const int nb  = nbx + nby + nbz;

    const bool fast = (G % 32 == 0) && (G % 4 == 0) &&
                      (ws_size >= (size_t)G * G2 * sizeof(float));

    if (fast) {
        float* Px = (float*)d_ws;
        transpose_RC<<<dim3(G2 / 32, G / 32), dim3(32, 8), 0, stream>>>(
            img, Px, G2, G);
        proj_fused<1><<<nb, B, 0, stream>>>(
            img, Px, xlors, ylors, zlors, center, size_, out,
            nx, ny, nz, nbx, nby, G, 0, 0, 0);
    } else {
        proj_fused<0><<<nb, B, 0, stream>>>(
            img, img, xlors, ylors, zlors, center, size_, out,
            nx, ny, nz, nbx, nby, G,
            /* x on original: perm (2,0,1) */ 1, G2, G);
    }
}

// Round 4
// 1497.215 us; speedup vs baseline: 4.8578x; 1.2008x over previous
//
#include <hip/hip_runtime.h>
#include <math.h>

// KERNEL_WIDTH = sqrt(9/pi) = 1.6925687506432297
#define KW2_F  2.8647889756541161f   // (9/pi)
#define KW_INV 0.5908179502964271f   // 1/KW
#define RW_F   1.6926f               // slightly >= KW (safe superset bound)
#define BIGD2  1e30f

// ---------------------------------------------------------------------------
// k-chunked (x4, float4) tube-of-response for one LOR. Requires s2 == 1 and
// n2 % 4 == 0. img indexed as jx*s0 + jy*s1 + k.
// Semantics: reference taps with w>0 satisfy dist < KW, and any such tap is
// provably inside the reference 5x5 window (|jx-round(fx)| <= 2 follows from
// |jx-fx| < KW + rounding 0.5 = 2.19). So iterating ALL in-bounds taps within
// radius RW of the segment and clamping w at 0 reproduces the reference sum
// exactly (up to fp association). No rint/window/bounds masks needed.
// ---------------------------------------------------------------------------
__device__ __forceinline__
float tor_lor4(const float* __restrict__ img,
               const float* __restrict__ L,
               float lo0, float lo1, float lo2,
               float vs0, float vs1, float vs2,
               int n0, int n1, int n2, int s0, int s1)
{
    const float inv_vs0 = 1.0f / vs0;
    const float inv_vs1 = 1.0f / vs1;

    const float p1x = L[0], p1y = L[1], p1z = L[2];
    const float p2x = L[3], p2y = L[4], p2z = L[5];
    const float dx = p2x - p1x, dy = p2y - p1y, dz = p2z - p1z;
    const float len = sqrtf(dx * dx + dy * dy + dz * dz);
    const float inv_dz = 1.0f / dz;
    const float step = vs2 * len * fabsf(inv_dz);

    float acc0 = 0.0f, acc1 = 0.0f, acc2 = 0.0f, acc3 = 0.0f;

    for (int k0 = 0; k0 < n2; k0 += 4) {
        float fx[4], fy[4];
#pragma unroll
        for (int j = 0; j < 4; ++j) {
            const float zc = lo2 + ((float)(k0 + j) + 0.5f) * vs2;
            const float t  = (zc - p1z) * inv_dz;
            fx[j] = (fmaf(t, dx, p1x) - lo0) * inv_vs0 - 0.5f;
            fy[j] = (fmaf(t, dy, p1y) - lo1) * inv_vs1 - 0.5f;
        }
        // fx,fy affine in k -> chunk extremes at endpoints.
        const float fxmin = fminf(fx[0], fx[3]), fxmax = fmaxf(fx[0], fx[3]);
        const float fymin = fminf(fy[0], fy[3]), fymax = fmaxf(fy[0], fy[3]);
        const int xlo = max(0,      (int)ceilf (fxmin - RW_F));
        const int xhi = min(n0 - 1, (int)floorf(fxmax + RW_F));
        const int ylo = max(0,      (int)ceilf (fymin - RW_F));
        const int yhi = min(n1 - 1, (int)floorf(fymax + RW_F));

        for (int jx = xlo; jx <= xhi; ++jx) {
            float ddx2[4];
#pragma unroll
            for (int j = 0; j < 4; ++j) {
                const float dxx = (float)jx - fx[j];
                ddx2[j] = dxx * dxx;
            }
            const float rowmin =
                fminf(fminf(ddx2[0], ddx2[1]), fminf(ddx2[2], ddx2[3]));
            if (rowmin >= KW2_F) continue;   // whole row weightless

            const float* rowp = img + jx * s0 + k0;

            for (int jy = ylo; jy <= yhi; ++jy) {
                float d2[4];
#pragma unroll
                for (int j = 0; j < 4; ++j) {
                    const float dyy = (float)jy - fy[j];
                    d2[j] = fmaf(dyy, dyy, ddx2[j]);
                }
                const float dmin =
                    fminf(fminf(d2[0], d2[1]), fminf(d2[2], d2[3]));
                if (dmin < KW2_F) {
                    const float4 v =
                        *reinterpret_cast<const float4*>(rowp + jy * s1);
                    float wg[4];
#pragma unroll
                    for (int j = 0; j < 4; ++j)
                        wg[j] = fmaxf(0.0f, fmaf(-sqrtf(d2[j]), KW_INV, 1.0f));
                    acc0 = fmaf(wg[0], v.x, acc0);
                    acc1 = fmaf(wg[1], v.y, acc1);
                    acc2 = fmaf(wg[2], v.z, acc2);
                    acc3 = fmaf(wg[3], v.w, acc3);
                }
            }
        }
    }
    return (acc0 + acc1 + acc2 + acc3) * step;
}

// Scalar guarded fallback (any strides / any n2).
__device__ __forceinline__
float tor_lor_s(const float* __restrict__ img,
                const float* __restrict__ L,
                float lo0, float lo1, float lo2,
                float vs0, float vs1, float vs2,
                int n0, int n1, int n2, int s0, int s1, int s2)
{
    const float inv_vs0 = 1.0f / vs0;
    const float inv_vs1 = 1.0f / vs1;
    const float p1x = L[0], p1y = L[1], p1z = L[2];
    const float p2x = L[3], p2y = L[4], p2z = L[5];
    const float dx = p2x - p1x, dy = p2y - p1y, dz = p2z - p1z;
    const float len = sqrtf(dx * dx + dy * dy + dz * dz);
    const float inv_dz = 1.0f / dz;
    const float step = vs2 * len * fabsf(inv_dz);

    float acc_total = 0.0f;
    for (int k = 0; k < n2; ++k) {
        const float zc = lo2 + ((float)k + 0.5f) * vs2;
        const float t  = (zc - p1z) * inv_dz;
        const float fx = (fmaf(t, dx, p1x) - lo0) * inv_vs0 - 0.5f;
        const float fy = (fmaf(t, dy, p1y) - lo1) * inv_vs1 - 0.5f;
        const int ix = (int)rintf(fx);
        const int iy = (int)rintf(fy);
        const int kb = k * s2;
        float acc = 0.0f;
#pragma unroll
        for (int o0 = -2; o0 <= 2; ++o0) {
            const int jx = ix + o0;
            if ((unsigned)jx >= (unsigned)n0) continue;
            const float dxx  = (float)jx - fx;
            const float ddx2 = dxx * dxx;
            if (ddx2 >= KW2_F) continue;
            const int xb = jx * s0 + kb;
#pragma unroll
            for (int o1 = -2; o1 <= 2; ++o1) {
                const int jy = iy + o1;
                if ((unsigned)jy >= (unsigned)n1) continue;
                const float dyy = (float)jy - fy;
                const float d2  = fmaf(dyy, dyy, ddx2);
                if (d2 < KW2_F) {
                    const float w = fmaf(-sqrtf(d2), KW_INV, 1.0f);
                    acc = fmaf(w, img[xb + jy * s1], acc);
                }
            }
        }
        acc_total += acc;
    }
    return acc_total * step;
}

// ---------------------------------------------------------------------------
// Fused launch: block ranges pick the LOR set. FOUR==1 -> float4 path
// (s2==1 for all sets; x uses the transposed copy imgX). B = 128.
// ---------------------------------------------------------------------------
template<int FOUR>
__global__ __launch_bounds__(128)
void proj_fused(const float* __restrict__ imgZ,
                const float* __restrict__ imgX,
                const float* __restrict__ xlors,
                const float* __restrict__ ylors,
                const float* __restrict__ zlors,
                const float* __restrict__ center,
                const float* __restrict__ size_,
                float* __restrict__ out,
                int nx, int ny, int nz,
                int nbx, int nby, int G,
                int xs0, int xs1, int xs2)  // x-set strides (scalar path)
{
    const int b = blockIdx.x;
    const int G2 = G * G;

    const float* img;
    const float* lors;
    float* op;
    int a0, a1, a2, s0, s1, s2;

    if (b < nbx) {            // px: perm (2,0,1)
        const int i = b * 128 + threadIdx.x;
        if (i >= nx) return;
        img = FOUR ? imgX : imgZ;
        lors = xlors + 6 * (size_t)i;  op = out + i;
        a0 = 2; a1 = 0; a2 = 1;
        if (FOUR) { s0 = G2; s1 = G; s2 = 1; }
        else      { s0 = xs0; s1 = xs1; s2 = xs2; }
    } else if (b < nbx + nby) {  // py: perm (1,0,2)
        const int i = (b - nbx) * 128 + threadIdx.x;
        if (i >= ny) return;
        img = imgZ; lors = ylors + 6 * (size_t)i;  op = out + nx + i;
        a0 = 1; a1 = 0; a2 = 2;  s0 = G; s1 = G2; s2 = 1;
    } else {                     // pz: identity
        const int i = (b - nbx - nby) * 128 + threadIdx.x;
        if (i >= nz) return;
        img = imgZ; lors = zlors + 6 * (size_t)i;  op = out + nx + ny + i;
        a0 = 0; a1 = 1; a2 = 2;  s0 = G2; s1 = G; s2 = 1;
    }

    const float S0 = size_[a0], S1 = size_[a1], S2 = size_[a2];
    const float vs0 = S0 / (float)G, vs1 = S1 / (float)G, vs2 = S2 / (float)G;
    const float lo0 = center[a0] - 0.5f * S0;
    const float lo1 = center[a1] - 0.5f * S1;
    const float lo2 = center[a2] - 0.5f * S2;

    float r;
    if (FOUR)
        r = tor_lor4(img, lors, lo0, lo1, lo2, vs0, vs1, vs2,
                     G, G, G, s0, s1);
    else
        r = tor_lor_s(img, lors, lo0, lo1, lo2, vs0, vs1, vs2,
                      G, G, G, s0, s1, s2);
    *op = r;
}

// 2D transpose in[R][C] -> out[C][R]; Px[c,i0,i1] = image[i0,i1,c]
// giving the x-perm with strides (G^2, G, 1). R, C divisible by 32.
__global__ __launch_bounds__(256)
void transpose_RC(const float* __restrict__ in, float* __restrict__ outp,
                  int R, int C)
{
    __shared__ float tile[32][33];
    const int rt = blockIdx.x * 32;
    const int ct = blockIdx.y * 32;
    const int tx = threadIdx.x;
    const int ty = threadIdx.y;   // block (32,8)
#pragma unroll
    for (int j = 0; j < 32; j += 8)
        tile[ty + j][tx] = in[(size_t)(rt + ty + j) * C + (ct + tx)];
    __syncthreads();
#pragma unroll
    for (int j = 0; j < 32; j += 8)
        outp[(size_t)(ct + ty + j) * R + (rt + tx)] = tile[tx][ty + j];
}

extern "C" void kernel_launch(void* const* d_in, const int* in_sizes, int n_in,
                              void* d_out, int out_size, void* d_ws, size_t ws_size,
                              hipStream_t stream)
{
    const float* img    = (const float*)d_in[0];
    const float* center = (const float*)d_in[2];
    const float* size_  = (const float*)d_in[3];
    const float* xlors  = (const float*)d_in[4];
    const float* ylors  = (const float*)d_in[5];
    const float* zlors  = (const float*)d_in[6];
    float* out = (float*)d_out;

    const int nx = in_sizes[4] / 6;
    const int ny = in_sizes[5] / 6;
    const int nz = in_sizes[6] / 6;

    int G = (int)lround(cbrt((double)in_sizes[0]));
    const int G2 = G * G;

    const int B = 128;
    const int nbx = (nx + B - 1) / B;
    const int nby = (ny + B - 1) / B;
    const int nbz = (nz + B - 1) / B;
    const int nb  = nbx + nby + nbz;

    const bool fast = (G % 32 == 0) &&
                      (ws_size >= (size_t)G * G2 * sizeof(float));

    if (fast) {
        float* Px = (float*)d_ws;
        transpose_RC<<<dim3(G2 / 32, G / 32), dim3(32, 8), 0, stream>>>(
            img, Px, G2, G);
        proj_fused<1><<<nb, B, 0, stream>>>(
            img, Px, xlors, ylors, zlors, center, size_, out,
            nx, ny, nz, nbx, nby, G, 0, 0, 0);
    } else {
        proj_fused<0><<<nb, B, 0, stream>>>(
            img, img, xlors, ylors, zlors, center, size_, out,
            nx, ny, nz, nbx, nby, G,
            /* x on original: perm (2,0,1) */ 1, G2, G);
    }
}